// Round 14
// baseline (256.351 us; speedup 1.0000x reference)
//
#include <hip/hip_runtime.h>
#include <hip/hip_cooperative_groups.h>
#include <stdint.h>

#define BATCH 8
#define MPTS 500000
#define NPTS (BATCH * MPTS)            // 4,000,000
#define NBQ 1024                       // 8 batches * (4*4*8) sub-blocks of 32x32x16
#define TP 8192                        // points per tile
#define NTILE ((NPTS + TP - 1) / TP)   // 489
#define HROW (NBQ + 1)                 // offsets row stride (last entry = tile cnt)
#define NIFACE 304                     // interfaces per batch: 96 + 96 + 112
#define NBND (BATCH * NIFACE)          // 2432 boundary items
#define NT 512                         // threads per block

namespace cg = cooperative_groups;

template <int NTT>
__device__ __forceinline__ void block_reduce2(float& tv, float& mse) {
    for (int off = 32; off > 0; off >>= 1) {
        tv  += __shfl_down(tv, off, 64);
        mse += __shfl_down(mse, off, 64);
    }
    __shared__ float stv[NTT / 64], sms[NTT / 64];
    int w = threadIdx.x >> 6, lane = threadIdx.x & 63;
    if (lane == 0) { stv[w] = tv; sms[w] = mse; }
    __syncthreads();
    if (threadIdx.x == 0) {
        float a = 0.f, m = 0.f;
        #pragma unroll
        for (int e = 0; e < NTT / 64; ++e) { a += stv[e]; m += sms[e]; }
        tv = a; mse = m;
    }
}

// aux = (q:10 | l:14); sub-block 32x32x16. aux < 2^24 -> 0xFFFFFFFF safe sentinel.
__device__ __forceinline__ uint32_t pack_aux(int b, int i, int j, int k) {
    uint32_t q = ((uint32_t)b << 7) | ((uint32_t)(i >> 5) << 5) |
                 ((uint32_t)(j >> 5) << 3) | (uint32_t)(k >> 4);
    uint32_t l = ((uint32_t)(i & 31) << 9) | ((uint32_t)(j & 31) << 4) | (uint32_t)(k & 15);
    return (q << 14) | l;
}

// LDS bank swizzle: line s = il*32+jl holds 16 dwords; group-of-4 index XORed
// with (s>>1) so wave-wide b128 reads spread across all 32 banks.
__device__ __forceinline__ int gaddr(int s, int kl) {
    return s * 16 + (kl & 3) + ((((kl >> 2) ^ (s >> 1)) & 3) << 2);
}
__device__ __forceinline__ int goff(int s, int c) {
    return ((c ^ (s >> 1)) & 3) << 2;
}

__device__ __forceinline__ uint32_t val16(float f) {
    return (__float_as_uint(f) + 0x8000u) >> 16;   // top-16 bits, round-half-up
}
__device__ __forceinline__ uint16_t top16(float f) {
    return (uint16_t)(__float_as_uint(f) >> 16);
}
__device__ __forceinline__ float f16up(uint16_t u) {
    return __uint_as_float(((uint32_t)u) << 16);
}

// One cooperative kernel: sort -> accum -> boundary -> final, grid.sync between.
__global__ void __launch_bounds__(NT, 4) fused_k(const int* __restrict__ idx,
                                                 const float* __restrict__ val,
                                                 uint32_t* __restrict__ hoff,
                                                 uint32_t* __restrict__ rec,
                                                 uint16_t* __restrict__ faces,
                                                 float2* __restrict__ pa,
                                                 float2* __restrict__ pb,
                                                 float* __restrict__ out) {
    __shared__ float g[16384];            // 64 KB, phase-aliased
    __shared__ uint32_t wtot[8];
    uint32_t* h   = (uint32_t*)g;         // [0, 1024)   sort counters/cursors
    uint32_t* srt = (uint32_t*)g + 1024;  // [1024, 9216) sorted records
    cg::grid_group grid = cg::this_grid();
    int tid = threadIdx.x;

    // ---------- phase 1: per-tile counting sort (rec + hoff) ----------
    for (int tile = blockIdx.x; tile < NTILE; tile += gridDim.x) {
        int p0 = tile * TP;
        int cnt = min(TP, NPTS - p0);     // multiple of 4
        for (int c = tid; c < NBQ; c += NT) h[c] = 0;
        __syncthreads();
        uint32_t a[16]; uint32_t vpk[8];
        int ng = cnt >> 2;
        #pragma unroll
        for (int e = 0; e < 4; ++e) {
            int gg = tid + e * NT;
            if (gg < ng) {
                int p = p0 + gg * 4;
                const int4* ip = (const int4*)(idx + (size_t)p * 3);
                int4 A = ip[0], B = ip[1], C = ip[2];
                float4 V = *(const float4*)(val + p);
                int b = p / MPTS;         // groups of 4 never straddle a batch
                a[4*e+0] = pack_aux(b, A.x, A.y, A.z);
                a[4*e+1] = pack_aux(b, A.w, B.x, B.y);
                a[4*e+2] = pack_aux(b, B.z, B.w, C.x);
                a[4*e+3] = pack_aux(b, C.y, C.z, C.w);
                vpk[2*e]   = val16(V.x) | (val16(V.y) << 16);
                vpk[2*e+1] = val16(V.z) | (val16(V.w) << 16);
                #pragma unroll
                for (int u = 0; u < 4; ++u) atomicAdd(&h[a[4*e+u] >> 14], 1u);
            } else {
                a[4*e+0] = a[4*e+1] = a[4*e+2] = a[4*e+3] = 0xFFFFFFFFu;
                vpk[2*e] = vpk[2*e+1] = 0u;
            }
        }
        __syncthreads();
        // pair-per-thread exclusive scan of 1024 counts (wave shuffles)
        int lane = tid & 63, wave = tid >> 6;
        int q0 = tid * 2;
        uint32_t c0 = h[q0], c1 = h[q0 + 1];
        uint32_t ps = c0 + c1, inc = ps;
        #pragma unroll
        for (int off = 1; off < 64; off <<= 1) {
            uint32_t n = __shfl_up(inc, off, 64);
            if (lane >= off) inc += n;
        }
        if (lane == 63) wtot[wave] = inc;
        __syncthreads();
        if (tid < 8) {
            uint32_t w = wtot[tid];
            #pragma unroll
            for (int off = 1; off < 8; off <<= 1) {
                uint32_t n = __shfl_up(w, off, 8);
                if (tid >= off) w += n;
            }
            wtot[tid] = w;                // inclusive wave totals
        }
        __syncthreads();
        uint32_t pstart = (wave ? wtot[wave - 1] : 0u) + inc - ps;
        uint32_t* hr = hoff + (size_t)tile * HROW;
        hr[q0] = pstart; hr[q0 + 1] = pstart + c0;
        if (tid == 0) hr[NBQ] = (uint32_t)cnt;
        h[q0] = pstart; h[q0 + 1] = pstart + c0;   // placement cursors
        __syncthreads();
        #pragma unroll
        for (int e = 0; e < 16; ++e) {
            if (a[e] != 0xFFFFFFFFu) {
                uint32_t qq = a[e] >> 14;
                uint32_t u = (vpk[e >> 1] >> ((e & 1) * 16)) & 0xFFFFu;
                srt[atomicAdd(&h[qq], 1u)] = (u << 16) | (a[e] & 16383u);
            }
        }
        __syncthreads();
        uint4* recq = (uint4*)(rec + (size_t)tile * TP);
        const uint4* sr4 = (const uint4*)srt;
        for (int s = tid; s < (cnt >> 2); s += NT) recq[s] = sr4[s];
        __syncthreads();
    }
    grid.sync();

    // ---------- phase 2: per-bucket accumulate + stencil + faces ----------
    for (int qb = blockIdx.x; qb < NBQ; qb += gridDim.x) {
        {
            float4 z = make_float4(0.f, 0.f, 0.f, 0.f);
            #pragma unroll
            for (int c = 0; c < 8; ++c)
                *(float4*)&g[(tid + c * NT) * 4] = z;
        }
        __syncthreads();
        {
            int grp = tid >> 3, r8 = tid & 7;     // 64 groups of 8 lanes
            for (int t = grp; t < NTILE; t += NT / 8) {
                const uint32_t* row = hoff + (size_t)t * HROW;
                uint32_t s0 = row[qb], s1 = row[qb + 1];
                const uint32_t* rp = rec + (size_t)t * TP;
                for (uint32_t r = s0 + r8; r < s1; r += 8) {
                    uint32_t e = rp[r];
                    int l = e & 16383;
                    atomicAdd(&g[gaddr(l >> 4, l & 15)], __uint_as_float(e & 0xFFFF0000u));
                }
            }
        }
        __syncthreads();
        float tv = 0.f, mse = 0.f;
        #pragma unroll
        for (int half = 0; half < 2; ++half) {
            int s = tid + half * NT;              // two lines per thread
            int jl = s & 31, il = s >> 5;
            bool jin = jl < 31, iin = il < 31;
            float own[16];
            #pragma unroll
            for (int c = 0; c < 4; ++c)
                *(float4*)&own[c * 4] = *(const float4*)&g[s * 16 + goff(s, c)];
            #pragma unroll
            for (int k = 0; k < 15; ++k) {
                float d = own[k + 1] - own[k]; tv += fabsf(d); mse += d * d;
            }
            #pragma unroll
            for (int hh = 0; hh < 2; ++hh) {
                if (jin) {
                    float jn[8];
                    *(float4*)&jn[0] = *(const float4*)&g[(s + 1) * 16 + goff(s + 1, 2 * hh)];
                    *(float4*)&jn[4] = *(const float4*)&g[(s + 1) * 16 + goff(s + 1, 2 * hh + 1)];
                    #pragma unroll
                    for (int k = 0; k < 8; ++k) {
                        float d = jn[k] - own[8 * hh + k]; tv += fabsf(d); mse += d * d;
                    }
                }
                if (iin) {
                    float inb[8];
                    *(float4*)&inb[0] = *(const float4*)&g[(s + 32) * 16 + goff(s + 32, 2 * hh)];
                    *(float4*)&inb[4] = *(const float4*)&g[(s + 32) * 16 + goff(s + 32, 2 * hh + 1)];
                    #pragma unroll
                    for (int k = 0; k < 8; ++k) {
                        float d = inb[k] - own[8 * hh + k]; tv += fabsf(d); mse += d * d;
                    }
                }
            }
        }
        // faces (ushort = top-16 float bits)
        {
            uint16_t* f = faces + (size_t)qb * 4096;
            int t = tid;                          // [0,512)
            int hi = t >> 4, lo = t & 15;
            f[t]        = top16(g[gaddr(hi, lo)]);             // i=0  (e=jl*16+kl)
            f[512 + t]  = top16(g[gaddr(992 + hi, lo)]);       // i=31
            f[1024 + t] = top16(g[gaddr(hi * 32, lo)]);        // j=0  (e=il*16+kl)
            f[1536 + t] = top16(g[gaddr(hi * 32 + 31, lo)]);   // j=31
            f[2048 + t]      = top16(g[gaddr(t, 0)]);          // k=0 (e=il*32+jl)
            f[2048 + NT + t] = top16(g[gaddr(t + NT, 0)]);
            f[3072 + t]      = top16(g[gaddr(t, 15)]);         // k=15
            f[3072 + NT + t] = top16(g[gaddr(t + NT, 15)]);
        }
        block_reduce2<NT>(tv, mse);
        if (tid == 0) pa[qb] = make_float2(tv, mse);
        __syncthreads();
    }
    grid.sync();

    // ---------- phase 3: cross-sub-block interfaces ----------
    for (int x = blockIdx.x; x < NBND; x += gridDim.x) {
        int b = x / NIFACE;
        int r = x - b * NIFACE;
        int qA, qB, fA, fB, elems;
        if (r < 96) {                       // axis i
            int s = r >> 5, u = (r >> 3) & 3, w = r & 7;
            qA = (b << 7) | (s << 5) | (u << 3) | w; qB = qA + 32;
            fA = 512; fB = 0; elems = 512;
        } else if (r < 192) {               // axis j
            int r2 = r - 96;
            int s = r2 >> 5, u = (r2 >> 3) & 3, w = r2 & 7;
            qA = (b << 7) | (u << 5) | (s << 3) | w; qB = qA + 8;
            fA = 1536; fB = 1024; elems = 512;
        } else {                            // axis k
            int r2 = r - 192;
            int s = r2 >> 4, u = (r2 >> 2) & 3, v = r2 & 3;
            qA = (b << 7) | (u << 5) | (v << 3) | s; qB = qA + 1;
            fA = 3072; fB = 2048; elems = 1024;
        }
        const uint16_t* pA = faces + (size_t)qA * 4096 + fA;
        const uint16_t* pB = faces + (size_t)qB * 4096 + fB;
        float tv = 0.f, mse = 0.f;
        for (int e = tid; e < elems; e += NT) {
            float d = f16up(pB[e]) - f16up(pA[e]);
            tv += fabsf(d); mse += d * d;
        }
        block_reduce2<NT>(tv, mse);
        if (tid == 0) pb[x] = make_float2(tv, mse);
        __syncthreads();                    // protect reduce buffers across items
    }
    grid.sync();

    // ---------- phase 4: final per-batch reduction ----------
    for (int b = blockIdx.x; b < BATCH; b += gridDim.x) {
        float tv = 0.f, mse = 0.f;
        const float2* A = pa + (size_t)b * (NBQ / BATCH);
        for (int i = tid; i < NBQ / BATCH; i += NT) { float2 v2 = A[i]; tv += v2.x; mse += v2.y; }
        const float2* P = pb + (size_t)b * NIFACE;
        for (int i = tid; i < NIFACE; i += NT) { float2 v2 = P[i]; tv += v2.x; mse += v2.y; }
        block_reduce2<NT>(tv, mse);
        if (tid == 0) {
            out[b]     = tv  * (1.f / 2097152.f);   // / X^3
            out[8 + b] = mse * (1.f / 32512.f);     // / (2X^2-2X)
        }
        __syncthreads();
    }
}

extern "C" void kernel_launch(void* const* d_in, const int* in_sizes, int n_in,
                              void* d_out, int out_size, void* d_ws, size_t ws_size,
                              hipStream_t stream) {
    const int*   indices = (const int*)d_in[0];   // (B, M, 3) int32
    const float* values  = (const float*)d_in[1]; // (B, M) float32
    float*       out     = (float*)d_out;         // (2, B) float32

    // workspace (~26 MiB), 256B-aligned sections
    char* wp = (char*)d_ws;
    uint32_t* hoff  = (uint32_t*)wp;                           // NTILE*HROW (2.0 MB)
    wp += (((size_t)NTILE * HROW * 4) + 255) & ~(size_t)255;
    float2*   pa    = (float2*)wp;                             // NBQ        (8 KB)
    wp += (NBQ * 8 + 255) & ~(size_t)255;
    float2*   pb    = (float2*)wp;                             // NBND       (19 KB)
    wp += ((size_t)NBND * 8 + 255) & ~(size_t)255;
    uint32_t* rec   = (uint32_t*)wp;                           // NTILE*TP   (16 MB)
    wp += (((size_t)NTILE * TP * 4) + 255) & ~(size_t)255;
    uint16_t* faces = (uint16_t*)wp;                           // NBQ*4096   (8 MB)

    // co-residency-safe grid size (deterministic every call; 256 CUs on MI355X)
    int maxPerCU = 0;
    hipOccupancyMaxActiveBlocksPerMultiprocessor(&maxPerCU, fused_k, NT, 0);
    if (maxPerCU < 1) maxPerCU = 1;
    int nblk = maxPerCU * 256;
    if (nblk > 512) nblk = 512;

    void* args[] = { (void*)&indices, (void*)&values, (void*)&hoff, (void*)&rec,
                     (void*)&faces, (void*)&pa, (void*)&pb, (void*)&out };
    hipLaunchCooperativeKernel(fused_k, dim3(nblk), dim3(NT), args, 0u, stream);
}

// Round 15
// 184.912 us; speedup vs baseline: 1.3863x; 1.3863x over previous
//
#include <hip/hip_runtime.h>
#include <stdint.h>

#define BATCH 8
#define MPTS 500000
#define NPTS (BATCH * MPTS)            // 4,000,000
#define NBQ 1024                       // 8 batches * (4*4*8) sub-blocks of 32x32x16
#define TP 16384                       // points per tile
#define NTILE ((NPTS + TP - 1) / TP)   // 245
#define HROW (NBQ + 1)                 // offsets row stride (last entry = tile cnt)
#define NIFACE 304                     // interfaces per batch: 96 + 96 + 112
#define NBND (BATCH * NIFACE)          // 2432 boundary blocks

template <int NT>
__device__ __forceinline__ void block_reduce2(float& tv, float& mse) {
    for (int off = 32; off > 0; off >>= 1) {
        tv  += __shfl_down(tv, off, 64);
        mse += __shfl_down(mse, off, 64);
    }
    __shared__ float stv[NT / 64], sms[NT / 64];
    int w = threadIdx.x >> 6, lane = threadIdx.x & 63;
    if (lane == 0) { stv[w] = tv; sms[w] = mse; }
    __syncthreads();
    if (threadIdx.x == 0) {
        float a = 0.f, m = 0.f;
        #pragma unroll
        for (int e = 0; e < NT / 64; ++e) { a += stv[e]; m += sms[e]; }
        tv = a; mse = m;
    }
}

// aux = (q:10 | l:14); sub-block 32x32x16. aux < 2^24 -> 0xFFFFFFFF safe sentinel.
__device__ __forceinline__ uint32_t pack_aux(int b, int i, int j, int k) {
    uint32_t q = ((uint32_t)b << 7) | ((uint32_t)(i >> 5) << 5) |
                 ((uint32_t)(j >> 5) << 3) | (uint32_t)(k >> 4);
    uint32_t l = ((uint32_t)(i & 31) << 9) | ((uint32_t)(j & 31) << 4) | (uint32_t)(k & 15);
    return (q << 14) | l;
}

// LDS bank swizzle: line s = il*32+jl holds 16 dwords; group-of-4 index XORed
// with (s>>1) so wave-wide b128 reads spread across all 32 banks.
__device__ __forceinline__ int gaddr(int s, int kl) {
    return s * 16 + (kl & 3) + ((((kl >> 2) ^ (s >> 1)) & 3) << 2);
}
__device__ __forceinline__ int goff(int s, int c) {
    return ((c ^ (s >> 1)) & 3) << 2;
}

// round float bits to top-16 (sign+exp+7man), round-half-up
__device__ __forceinline__ uint32_t val16(float f) {
    return (__float_as_uint(f) + 0x8000u) >> 16;
}
__device__ __forceinline__ float f16up(uint16_t u) {
    return __uint_as_float(((uint32_t)u) << 16);
}

// K1: fused per-tile hist + local exclusive scan + LDS counting sort + coalesced
// writeout. Record = (val16 << 16) | local14 (bits 14-15 zero). Also zeroes bcnt.
__global__ void __launch_bounds__(1024, 8) sort_k(const int* __restrict__ idx,
                                                  const float* __restrict__ val,
                                                  uint32_t* __restrict__ hoff,
                                                  uint32_t* __restrict__ rec,
                                                  uint32_t* __restrict__ bcnt) {
    __shared__ uint32_t h[NBQ];     // counts -> placement cursors
    __shared__ uint32_t wtot[16];
    __shared__ uint32_t srt[TP];    // sorted packed records (64 KB)
    int tile = blockIdx.x;
    if (tile == 0 && threadIdx.x < BATCH) bcnt[threadIdx.x] = 0u;  // reset counters
    int p0 = tile * TP;
    int cnt = min(TP, NPTS - p0);   // always a multiple of 4
    h[threadIdx.x] = 0;
    __syncthreads();
    // phase 1: vectorized loads (4 points = 3 int4 + 1 float4), LDS histogram.
    uint32_t a[16]; uint32_t vpk[8];
    int ng = cnt >> 2;
    #pragma unroll
    for (int e = 0; e < 4; ++e) {
        int g = threadIdx.x + e * 1024;
        if (g < ng) {
            int p = p0 + g * 4;
            const int4* ip = (const int4*)(idx + (size_t)p * 3);
            int4 A = ip[0], B = ip[1], C = ip[2];
            float4 V = *(const float4*)(val + p);
            int b = p / MPTS;       // groups of 4 never straddle a batch
            a[4*e+0] = pack_aux(b, A.x, A.y, A.z);
            a[4*e+1] = pack_aux(b, A.w, B.x, B.y);
            a[4*e+2] = pack_aux(b, B.z, B.w, C.x);
            a[4*e+3] = pack_aux(b, C.y, C.z, C.w);
            vpk[2*e]     = val16(V.x) | (val16(V.y) << 16);
            vpk[2*e + 1] = val16(V.z) | (val16(V.w) << 16);
            #pragma unroll
            for (int u = 0; u < 4; ++u) atomicAdd(&h[a[4*e+u] >> 14], 1u);
        } else {
            a[4*e+0] = a[4*e+1] = a[4*e+2] = a[4*e+3] = 0xFFFFFFFFu;
            vpk[2*e] = vpk[2*e + 1] = 0u;
        }
    }
    __syncthreads();
    // phase 2: block exclusive scan of 1024 counts (wave shuffles, 2 barriers)
    int q = threadIdx.x, lane = q & 63, wave = q >> 6;
    uint32_t cq = h[q];
    uint32_t inc = cq;
    #pragma unroll
    for (int off = 1; off < 64; off <<= 1) {
        uint32_t n = __shfl_up(inc, off, 64);
        if (lane >= off) inc += n;
    }
    if (lane == 63) wtot[wave] = inc;
    __syncthreads();
    if (q < 16) {
        uint32_t w = wtot[q];
        #pragma unroll
        for (int off = 1; off < 16; off <<= 1) {
            uint32_t n = __shfl_up(w, off, 16);
            if (q >= off) w += n;
        }
        wtot[q] = w;
    }
    __syncthreads();
    uint32_t lstart = (wave ? wtot[wave - 1] : 0u) + inc - cq;
    hoff[(size_t)tile * HROW + q] = lstart;          // tile-local start offset
    if (q == 0) hoff[(size_t)tile * HROW + NBQ] = (uint32_t)cnt;
    h[q] = lstart;                                    // placement cursor
    __syncthreads();
    // phase 3: place into LDS sorted order
    #pragma unroll
    for (int e = 0; e < 16; ++e) {
        if (a[e] != 0xFFFFFFFFu) {
            uint32_t qq = a[e] >> 14;
            uint32_t u = (vpk[e >> 1] >> ((e & 1) * 16)) & 0xFFFFu;
            srt[atomicAdd(&h[qq], 1u)] = (u << 16) | (a[e] & 16383u);
        }
    }
    __syncthreads();
    // phase 4: fully coalesced linear writeout (uint4)
    uint4* recq = (uint4*)(rec + (size_t)tile * TP);
    const uint4* sr4 = (const uint4*)srt;
    for (int s = threadIdx.x; s < (cnt >> 2); s += 1024) recq[s] = sr4[s];
}

// K2: per-bucket LDS accumulate (swizzled 64 KB). 8-lane group grp handles
// tiles grp and grp+128 (NTILE=245 -> at most 2), runs of ~16 records each.
__global__ void __launch_bounds__(1024, 8) accum_k(const uint32_t* __restrict__ rec,
                                                   const uint32_t* __restrict__ hoff,
                                                   uint16_t* __restrict__ faces,
                                                   float2* __restrict__ pa) {
    __shared__ float g[16384];   // voxel (s = il*32+jl, kl) at gaddr(s,kl)
    int qb = blockIdx.x;
    {
        float4 z = make_float4(0.f, 0.f, 0.f, 0.f);
        #pragma unroll
        for (int c = 0; c < 4; ++c)
            *(float4*)&g[(threadIdx.x + c * 1024) * 4] = z;
    }
    __syncthreads();
    {
        int grp = threadIdx.x >> 3;      // 0..127
        int r8  = threadIdx.x & 7;
        const uint32_t* rowA = hoff + (size_t)grp * HROW;
        uint32_t a0 = rowA[qb], a1 = rowA[qb + 1];
        const uint32_t* rpA = rec + (size_t)grp * TP;
        int tB = grp + 128;
        uint32_t b0 = 0, b1 = 0;
        const uint32_t* rpB = nullptr;
        if (tB < NTILE) {
            const uint32_t* rowB = hoff + (size_t)tB * HROW;
            b0 = rowB[qb]; b1 = rowB[qb + 1];
            rpB = rec + (size_t)tB * TP;
        }
        for (uint32_t r = a0 + r8; r < a1; r += 8) {
            uint32_t e = rpA[r];
            int l = e & 16383;
            atomicAdd(&g[gaddr(l >> 4, l & 15)], __uint_as_float(e & 0xFFFF0000u));
        }
        if (rpB) {
            for (uint32_t r = b0 + r8; r < b1; r += 8) {
                uint32_t e = rpB[r];
                int l = e & 16383;
                atomicAdd(&g[gaddr(l >> 4, l & 15)], __uint_as_float(e & 0xFFFF0000u));
            }
        }
    }
    __syncthreads();
    // stencil: thread t owns line s = t (il = t>>5, jl = t&31)
    float tv = 0.f, mse = 0.f;
    {
        int s = threadIdx.x;
        int jl = s & 31, il = s >> 5;
        bool jin = jl < 31, iin = il < 31;
        float own[16];
        #pragma unroll
        for (int c = 0; c < 4; ++c)
            *(float4*)&own[c * 4] = *(const float4*)&g[s * 16 + goff(s, c)];
        #pragma unroll
        for (int k = 0; k < 15; ++k) {
            float d = own[k + 1] - own[k]; tv += fabsf(d); mse += d * d;
        }
        #pragma unroll
        for (int hh = 0; hh < 2; ++hh) {
            if (jin) {
                float jn[8];
                *(float4*)&jn[0] = *(const float4*)&g[(s + 1) * 16 + goff(s + 1, 2 * hh)];
                *(float4*)&jn[4] = *(const float4*)&g[(s + 1) * 16 + goff(s + 1, 2 * hh + 1)];
                #pragma unroll
                for (int k = 0; k < 8; ++k) {
                    float d = jn[k] - own[8 * hh + k]; tv += fabsf(d); mse += d * d;
                }
            }
            if (iin) {
                float inb[8];
                *(float4*)&inb[0] = *(const float4*)&g[(s + 32) * 16 + goff(s + 32, 2 * hh)];
                *(float4*)&inb[4] = *(const float4*)&g[(s + 32) * 16 + goff(s + 32, 2 * hh + 1)];
                #pragma unroll
                for (int k = 0; k < 8; ++k) {
                    float d = inb[k] - own[8 * hh + k]; tv += fabsf(d); mse += d * d;
                }
            }
        }
    }
    // faces (ushort = top-16 float bits)
    {
        uint16_t* f = faces + (size_t)qb * 4096;
        int t = threadIdx.x;
        if (t < 512) {
            int hi = t >> 4, lo = t & 15;
            f[t]        = (uint16_t)(__float_as_uint(g[gaddr(hi, lo)]) >> 16);
            f[512 + t]  = (uint16_t)(__float_as_uint(g[gaddr(992 + hi, lo)]) >> 16);
            f[1024 + t] = (uint16_t)(__float_as_uint(g[gaddr(hi * 32, lo)]) >> 16);
            f[1536 + t] = (uint16_t)(__float_as_uint(g[gaddr(hi * 32 + 31, lo)]) >> 16);
        }
        f[2048 + t] = (uint16_t)(__float_as_uint(g[gaddr(t, 0)]) >> 16);
        f[3072 + t] = (uint16_t)(__float_as_uint(g[gaddr(t, 15)]) >> 16);
    }
    block_reduce2<1024>(tv, mse);
    if (threadIdx.x == 0) pa[qb] = make_float2(tv, mse);
}

// K3: cross-sub-block interface diffs + fused final reduction (last block per
// batch, via device-scope done-counter).
__global__ void __launch_bounds__(256) boundary_k(const uint16_t* __restrict__ faces,
                                                  const float2* __restrict__ pa,
                                                  float2* __restrict__ pb,
                                                  uint32_t* __restrict__ bcnt,
                                                  float* __restrict__ out) {
    __shared__ bool last;
    int x = blockIdx.x;
    int b = x / NIFACE;
    int r = x - b * NIFACE;
    int qA, qB, fA, fB, elems;
    if (r < 96) {                       // axis i
        int s = r >> 5, u = (r >> 3) & 3, w = r & 7;
        qA = (b << 7) | (s << 5) | (u << 3) | w; qB = qA + 32;
        fA = 512; fB = 0; elems = 512;
    } else if (r < 192) {               // axis j
        int r2 = r - 96;
        int s = r2 >> 5, u = (r2 >> 3) & 3, w = r2 & 7;
        qA = (b << 7) | (u << 5) | (s << 3) | w; qB = qA + 8;
        fA = 1536; fB = 1024; elems = 512;
    } else {                            // axis k
        int r2 = r - 192;
        int s = r2 >> 4, u = (r2 >> 2) & 3, v = r2 & 3;
        qA = (b << 7) | (u << 5) | (v << 3) | s; qB = qA + 1;
        fA = 3072; fB = 2048; elems = 1024;
    }
    const uint16_t* pA = faces + (size_t)qA * 4096 + fA;
    const uint16_t* pB = faces + (size_t)qB * 4096 + fB;
    float tv = 0.f, mse = 0.f;
    for (int e = threadIdx.x; e < elems; e += 256) {
        float d = f16up(pB[e]) - f16up(pA[e]);
        tv += fabsf(d); mse += d * d;
    }
    block_reduce2<256>(tv, mse);
    if (threadIdx.x == 0) {
        pb[x] = make_float2(tv, mse);
        __threadfence();                              // release pb[x]
        uint32_t old = atomicAdd(&bcnt[b], 1u);       // device-scope
        last = (old == NIFACE - 1);
    }
    __syncthreads();
    if (last) {                                       // final reduction for batch b
        __threadfence();                              // acquire others' pb writes
        float t2 = 0.f, m2 = 0.f;
        const float2* A = pa + (size_t)b * (NBQ / BATCH);
        for (int i = threadIdx.x; i < NBQ / BATCH; i += 256) { float2 v = A[i]; t2 += v.x; m2 += v.y; }
        const float2* P = pb + (size_t)b * NIFACE;
        for (int i = threadIdx.x; i < NIFACE; i += 256) { float2 v = P[i]; t2 += v.x; m2 += v.y; }
        block_reduce2<256>(t2, m2);
        if (threadIdx.x == 0) {
            out[b]     = t2 * (1.f / 2097152.f);   // / X^3
            out[8 + b] = m2 * (1.f / 32512.f);     // / (2X^2-2X)
        }
    }
}

extern "C" void kernel_launch(void* const* d_in, const int* in_sizes, int n_in,
                              void* d_out, int out_size, void* d_ws, size_t ws_size,
                              hipStream_t stream) {
    const int*   indices = (const int*)d_in[0];   // (B, M, 3) int32
    const float* values  = (const float*)d_in[1]; // (B, M) float32
    float*       out     = (float*)d_out;         // (2, B) float32

    // workspace (~26 MiB), 256B-aligned sections
    char* wp = (char*)d_ws;
    uint32_t* hoff  = (uint32_t*)wp;                           // NTILE*HROW (1.0 MB)
    wp += (((size_t)NTILE * HROW * 4) + 255) & ~(size_t)255;
    float2*   pa    = (float2*)wp;                             // NBQ        (8 KB)
    wp += (NBQ * 8 + 255) & ~(size_t)255;
    float2*   pb    = (float2*)wp;                             // NBND       (19 KB)
    wp += ((size_t)NBND * 8 + 255) & ~(size_t)255;
    uint32_t* bcnt  = (uint32_t*)wp;                           // BATCH
    wp += (BATCH * 4 + 255) & ~(size_t)255;
    uint32_t* rec   = (uint32_t*)wp;                           // NTILE*TP   (16 MB)
    wp += (((size_t)NTILE * TP * 4) + 255) & ~(size_t)255;
    uint16_t* faces = (uint16_t*)wp;                           // NBQ*4096   (8 MB)

    sort_k    <<<NTILE, 1024, 0, stream>>>(indices, values, hoff, rec, bcnt);
    accum_k   <<<NBQ,   1024, 0, stream>>>(rec, hoff, faces, pa);
    boundary_k<<<NBND,  256,  0, stream>>>(faces, pa, pb, bcnt, out);
}

// Round 16
// 135.919 us; speedup vs baseline: 1.8861x; 1.3605x over previous
//
#include <hip/hip_runtime.h>
#include <stdint.h>

#define BATCH 8
#define MPTS 500000
#define NPTS (BATCH * MPTS)            // 4,000,000
#define NBQ 1024                       // 8 batches * (4*4*8) sub-blocks of 32x32x16
#define TP 16384                       // points per tile
#define NTILE ((NPTS + TP - 1) / TP)   // 245
#define HROW (NBQ + 1)                 // offsets row stride (last entry = tile cnt)
#define NIFACE 304                     // interfaces per batch: 96 + 96 + 112
#define NBND (BATCH * NIFACE)          // 2432 boundary blocks

template <int NT>
__device__ __forceinline__ void block_reduce2(float& tv, float& mse) {
    for (int off = 32; off > 0; off >>= 1) {
        tv  += __shfl_down(tv, off, 64);
        mse += __shfl_down(mse, off, 64);
    }
    __shared__ float stv[NT / 64], sms[NT / 64];
    int w = threadIdx.x >> 6, lane = threadIdx.x & 63;
    if (lane == 0) { stv[w] = tv; sms[w] = mse; }
    __syncthreads();
    if (threadIdx.x == 0) {
        float a = 0.f, m = 0.f;
        #pragma unroll
        for (int e = 0; e < NT / 64; ++e) { a += stv[e]; m += sms[e]; }
        tv = a; mse = m;
    }
}

// aux = (q:10 | l:14); sub-block 32x32x16. aux < 2^24 -> 0xFFFFFFFF safe sentinel.
__device__ __forceinline__ uint32_t pack_aux(int b, int i, int j, int k) {
    uint32_t q = ((uint32_t)b << 7) | ((uint32_t)(i >> 5) << 5) |
                 ((uint32_t)(j >> 5) << 3) | (uint32_t)(k >> 4);
    uint32_t l = ((uint32_t)(i & 31) << 9) | ((uint32_t)(j & 31) << 4) | (uint32_t)(k & 15);
    return (q << 14) | l;
}

// LDS bank swizzle: line s = il*32+jl holds 16 dwords; group-of-4 index XORed
// with (s>>1) so wave-wide b128 reads spread across all 32 banks.
__device__ __forceinline__ int gaddr(int s, int kl) {
    return s * 16 + (kl & 3) + ((((kl >> 2) ^ (s >> 1)) & 3) << 2);
}
__device__ __forceinline__ int goff(int s, int c) {
    return ((c ^ (s >> 1)) & 3) << 2;
}

// round float bits to top-16 (sign+exp+7man), round-half-up
__device__ __forceinline__ uint32_t val16(float f) {
    return (__float_as_uint(f) + 0x8000u) >> 16;
}

// K1: fused per-tile hist + local exclusive scan + LDS counting sort + coalesced
// writeout. Record = (val16 << 16) | local14 (bits 14-15 zero).
__global__ void __launch_bounds__(1024, 8) sort_k(const int* __restrict__ idx,
                                                  const float* __restrict__ val,
                                                  uint32_t* __restrict__ hoff,
                                                  uint32_t* __restrict__ rec) {
    __shared__ uint32_t h[NBQ];     // counts -> placement cursors
    __shared__ uint32_t wtot[16];
    __shared__ uint32_t srt[TP];    // sorted packed records (64 KB)
    int tile = blockIdx.x;
    int p0 = tile * TP;
    int cnt = min(TP, NPTS - p0);   // always a multiple of 4
    h[threadIdx.x] = 0;
    __syncthreads();
    // phase 1: vectorized loads (4 points = 3 int4 + 1 float4), LDS histogram.
    // Hold 16 aux (24-bit) + 16 vals packed 16-bit into vpk[8].
    uint32_t a[16]; uint32_t vpk[8];
    int ng = cnt >> 2;
    #pragma unroll
    for (int e = 0; e < 4; ++e) {
        int g = threadIdx.x + e * 1024;
        if (g < ng) {
            int p = p0 + g * 4;
            const int4* ip = (const int4*)(idx + (size_t)p * 3);
            int4 A = ip[0], B = ip[1], C = ip[2];
            float4 V = *(const float4*)(val + p);
            int b = p / MPTS;       // groups of 4 never straddle a batch
            a[4*e+0] = pack_aux(b, A.x, A.y, A.z);
            a[4*e+1] = pack_aux(b, A.w, B.x, B.y);
            a[4*e+2] = pack_aux(b, B.z, B.w, C.x);
            a[4*e+3] = pack_aux(b, C.y, C.z, C.w);
            vpk[2*e]     = val16(V.x) | (val16(V.y) << 16);
            vpk[2*e + 1] = val16(V.z) | (val16(V.w) << 16);
            #pragma unroll
            for (int u = 0; u < 4; ++u) atomicAdd(&h[a[4*e+u] >> 14], 1u);
        } else {
            a[4*e+0] = a[4*e+1] = a[4*e+2] = a[4*e+3] = 0xFFFFFFFFu;
            vpk[2*e] = vpk[2*e + 1] = 0u;
        }
    }
    __syncthreads();
    // phase 2: block exclusive scan of 1024 counts (wave shuffles, 2 barriers)
    int q = threadIdx.x, lane = q & 63, wave = q >> 6;
    uint32_t cq = h[q];
    uint32_t inc = cq;
    #pragma unroll
    for (int off = 1; off < 64; off <<= 1) {
        uint32_t n = __shfl_up(inc, off, 64);
        if (lane >= off) inc += n;
    }
    if (lane == 63) wtot[wave] = inc;
    __syncthreads();
    if (q < 16) {
        uint32_t w = wtot[q];
        #pragma unroll
        for (int off = 1; off < 16; off <<= 1) {
            uint32_t n = __shfl_up(w, off, 16);
            if (q >= off) w += n;
        }
        wtot[q] = w;
    }
    __syncthreads();
    uint32_t lstart = (wave ? wtot[wave - 1] : 0u) + inc - cq;
    hoff[(size_t)tile * HROW + q] = lstart;          // tile-local start offset
    if (q == 0) hoff[(size_t)tile * HROW + NBQ] = (uint32_t)cnt;
    h[q] = lstart;                                    // placement cursor
    __syncthreads();
    // phase 3: place into LDS sorted order
    #pragma unroll
    for (int e = 0; e < 16; ++e) {
        if (a[e] != 0xFFFFFFFFu) {
            uint32_t qq = a[e] >> 14;
            uint32_t u = (vpk[e >> 1] >> ((e & 1) * 16)) & 0xFFFFu;
            srt[atomicAdd(&h[qq], 1u)] = (u << 16) | (a[e] & 16383u);
        }
    }
    __syncthreads();
    // phase 4: fully coalesced linear writeout (uint4)
    uint4* recq = (uint4*)(rec + (size_t)tile * TP);
    const uint4* sr4 = (const uint4*)srt;
    for (int s = threadIdx.x; s < (cnt >> 2); s += 1024) recq[s] = sr4[s];
}

// K2: per-bucket LDS accumulate (swizzled 64 KB). 8-lane group grp handles
// tiles grp and grp+128 (NTILE=245 -> at most 2), runs of ~16 records each.
__global__ void __launch_bounds__(1024, 8) accum_k(const uint32_t* __restrict__ rec,
                                                   const uint32_t* __restrict__ hoff,
                                                   uint16_t* __restrict__ faces,
                                                   float2* __restrict__ pa) {
    __shared__ float g[16384];   // voxel (s = il*32+jl, kl) at gaddr(s,kl)
    int qb = blockIdx.x;
    {
        float4 z = make_float4(0.f, 0.f, 0.f, 0.f);
        #pragma unroll
        for (int c = 0; c < 4; ++c)
            *(float4*)&g[(threadIdx.x + c * 1024) * 4] = z;
    }
    __syncthreads();
    {
        int grp = threadIdx.x >> 3;      // 0..127
        int r8  = threadIdx.x & 7;
        // tile A = grp (always < 245), tile B = grp + 128 (valid if < 245)
        const uint32_t* rowA = hoff + (size_t)grp * HROW;
        uint32_t a0 = rowA[qb], a1 = rowA[qb + 1];
        const uint32_t* rpA = rec + (size_t)grp * TP;
        int tB = grp + 128;
        uint32_t b0 = 0, b1 = 0;
        const uint32_t* rpB = nullptr;
        if (tB < NTILE) {
            const uint32_t* rowB = hoff + (size_t)tB * HROW;
            b0 = rowB[qb]; b1 = rowB[qb + 1];
            rpB = rec + (size_t)tB * TP;
        }
        for (uint32_t r = a0 + r8; r < a1; r += 8) {
            uint32_t e = rpA[r];
            int l = e & 16383;
            atomicAdd(&g[gaddr(l >> 4, l & 15)], __uint_as_float(e & 0xFFFF0000u));
        }
        if (rpB) {
            for (uint32_t r = b0 + r8; r < b1; r += 8) {
                uint32_t e = rpB[r];
                int l = e & 16383;
                atomicAdd(&g[gaddr(l >> 4, l & 15)], __uint_as_float(e & 0xFFFF0000u));
            }
        }
    }
    __syncthreads();
    // stencil: thread t owns line s = t (il = t>>5, jl = t&31)
    float tv = 0.f, mse = 0.f;
    {
        int s = threadIdx.x;
        int jl = s & 31, il = s >> 5;
        bool jin = jl < 31, iin = il < 31;
        float own[16];
        #pragma unroll
        for (int c = 0; c < 4; ++c)
            *(float4*)&own[c * 4] = *(const float4*)&g[s * 16 + goff(s, c)];
        #pragma unroll
        for (int k = 0; k < 15; ++k) {
            float d = own[k + 1] - own[k]; tv += fabsf(d); mse += d * d;
        }
        #pragma unroll
        for (int hh = 0; hh < 2; ++hh) {
            if (jin) {
                float jn[8];
                *(float4*)&jn[0] = *(const float4*)&g[(s + 1) * 16 + goff(s + 1, 2 * hh)];
                *(float4*)&jn[4] = *(const float4*)&g[(s + 1) * 16 + goff(s + 1, 2 * hh + 1)];
                #pragma unroll
                for (int k = 0; k < 8; ++k) {
                    float d = jn[k] - own[8 * hh + k]; tv += fabsf(d); mse += d * d;
                }
            }
            if (iin) {
                float inb[8];
                *(float4*)&inb[0] = *(const float4*)&g[(s + 32) * 16 + goff(s + 32, 2 * hh)];
                *(float4*)&inb[4] = *(const float4*)&g[(s + 32) * 16 + goff(s + 32, 2 * hh + 1)];
                #pragma unroll
                for (int k = 0; k < 8; ++k) {
                    float d = inb[k] - own[8 * hh + k]; tv += fabsf(d); mse += d * d;
                }
            }
        }
    }
    // faces (ushort = top-16 float bits): layout as before
    {
        uint16_t* f = faces + (size_t)qb * 4096;
        int t = threadIdx.x;
        if (t < 512) {
            int hi = t >> 4, lo = t & 15;
            f[t]        = (uint16_t)(__float_as_uint(g[gaddr(hi, lo)]) >> 16);
            f[512 + t]  = (uint16_t)(__float_as_uint(g[gaddr(992 + hi, lo)]) >> 16);
            f[1024 + t] = (uint16_t)(__float_as_uint(g[gaddr(hi * 32, lo)]) >> 16);
            f[1536 + t] = (uint16_t)(__float_as_uint(g[gaddr(hi * 32 + 31, lo)]) >> 16);
        }
        f[2048 + t] = (uint16_t)(__float_as_uint(g[gaddr(t, 0)]) >> 16);
        f[3072 + t] = (uint16_t)(__float_as_uint(g[gaddr(t, 15)]) >> 16);
    }
    block_reduce2<1024>(tv, mse);
    if (threadIdx.x == 0) pa[qb] = make_float2(tv, mse);
}

__device__ __forceinline__ float f16up(uint16_t u) {
    return __uint_as_float(((uint32_t)u) << 16);
}

// K3: cross-sub-block interface diffs from face arrays (batch-major partials)
__global__ void __launch_bounds__(256) boundary_k(const uint16_t* __restrict__ faces,
                                                  float2* __restrict__ pb) {
    int x = blockIdx.x;
    int b = x / NIFACE;
    int r = x - b * NIFACE;
    int qA, qB, fA, fB, elems;
    if (r < 96) {                       // axis i
        int s = r >> 5, u = (r >> 3) & 3, w = r & 7;
        qA = (b << 7) | (s << 5) | (u << 3) | w; qB = qA + 32;
        fA = 512; fB = 0; elems = 512;
    } else if (r < 192) {               // axis j
        int r2 = r - 96;
        int s = r2 >> 5, u = (r2 >> 3) & 3, w = r2 & 7;
        qA = (b << 7) | (u << 5) | (s << 3) | w; qB = qA + 8;
        fA = 1536; fB = 1024; elems = 512;
    } else {                            // axis k
        int r2 = r - 192;
        int s = r2 >> 4, u = (r2 >> 2) & 3, v = r2 & 3;
        qA = (b << 7) | (u << 5) | (v << 3) | s; qB = qA + 1;
        fA = 3072; fB = 2048; elems = 1024;
    }
    const uint16_t* pA = faces + (size_t)qA * 4096 + fA;
    const uint16_t* pB = faces + (size_t)qB * 4096 + fB;
    float tv = 0.f, mse = 0.f;
    for (int e = threadIdx.x; e < elems; e += 256) {
        float d = f16up(pB[e]) - f16up(pA[e]);
        tv += fabsf(d); mse += d * d;
    }
    block_reduce2<256>(tv, mse);
    if (threadIdx.x == 0) pb[x] = make_float2(tv, mse);
}

// K4: final reduction — one block per batch, no atomics
__global__ void __launch_bounds__(256) final_k(const float2* __restrict__ pa,
                                               const float2* __restrict__ pb,
                                               float* __restrict__ out) {
    int b = blockIdx.x;
    float tv = 0.f, mse = 0.f;
    const float2* a = pa + (size_t)b * (NBQ / BATCH);
    for (int i = threadIdx.x; i < NBQ / BATCH; i += 256) { float2 v = a[i]; tv += v.x; mse += v.y; }
    const float2* p = pb + (size_t)b * NIFACE;
    for (int i = threadIdx.x; i < NIFACE; i += 256) { float2 v = p[i]; tv += v.x; mse += v.y; }
    block_reduce2<256>(tv, mse);
    if (threadIdx.x == 0) {
        out[b]     = tv  * (1.f / 2097152.f);   // / X^3
        out[8 + b] = mse * (1.f / 32512.f);     // / (2X^2-2X)
    }
}

extern "C" void kernel_launch(void* const* d_in, const int* in_sizes, int n_in,
                              void* d_out, int out_size, void* d_ws, size_t ws_size,
                              hipStream_t stream) {
    const int*   indices = (const int*)d_in[0];   // (B, M, 3) int32
    const float* values  = (const float*)d_in[1]; // (B, M) float32
    float*       out     = (float*)d_out;         // (2, B) float32

    // workspace (~26 MiB), 256B-aligned sections
    char* wp = (char*)d_ws;
    uint32_t* hoff  = (uint32_t*)wp;                           // NTILE*HROW (1.0 MB)
    wp += (((size_t)NTILE * HROW * 4) + 255) & ~(size_t)255;
    float2*   pa    = (float2*)wp;                             // NBQ        (8 KB)
    wp += (NBQ * 8 + 255) & ~(size_t)255;
    float2*   pb    = (float2*)wp;                             // NBND       (19 KB)
    wp += ((size_t)NBND * 8 + 255) & ~(size_t)255;
    uint32_t* rec   = (uint32_t*)wp;                           // NPTS+pad   (16 MB)
    wp += (((size_t)NTILE * TP * 4) + 255) & ~(size_t)255;
    uint16_t* faces = (uint16_t*)wp;                           // NBQ*4096   (8 MB)

    sort_k    <<<NTILE, 1024, 0, stream>>>(indices, values, hoff, rec);
    accum_k   <<<NBQ,   1024, 0, stream>>>(rec, hoff, faces, pa);
    boundary_k<<<NBND,  256,  0, stream>>>(faces, pb);
    final_k   <<<BATCH, 256,  0, stream>>>(pa, pb, out);
}